// Round 6
// baseline (139.213 us; speedup 1.0000x reference)
//
#include <hip/hip_runtime.h>

#define Nn 1024
#define Cc 256
#define Hh 4
#define Dd 64
#define HD 256
#define LOG2E 1.4426950408889634f
#define WSTRIDE 264   // u16 stride for LDS W tile

typedef unsigned short u16;
typedef unsigned int u32;
typedef unsigned char u8;
typedef __bf16 bf16x2 __attribute__((ext_vector_type(2)));
typedef __bf16 bf16x8 __attribute__((ext_vector_type(8)));
typedef float f32x4 __attribute__((ext_vector_type(4)));
typedef u16 u16x8 __attribute__((ext_vector_type(8)));
typedef u32 u32x4 __attribute__((ext_vector_type(4)));

__device__ __forceinline__ float bf2f(u16 v) {
    return __builtin_bit_cast(float, (u32)v << 16);
}
__device__ __forceinline__ u16 f2bf(float f) {
    u32 u = __builtin_bit_cast(u32, f);
    return (u16)((u + 0x7fffu + ((u >> 16) & 1u)) >> 16);
}
__device__ __forceinline__ u32 pk_bf16(float a, float b) {
#if __has_builtin(__builtin_amdgcn_cvt_pk_bf16_f32)
    bf16x2 v = __builtin_amdgcn_cvt_pk_bf16_f32(a, b);
    return __builtin_bit_cast(u32, v);
#else
    return (u32)f2bf(a) | ((u32)f2bf(b) << 16);
#endif
}
__device__ __forceinline__ float fast_exp2(float x) {
#if __has_builtin(__builtin_amdgcn_exp2f)
    return __builtin_amdgcn_exp2f(x);
#else
    float r; asm("v_exp_f32 %0, %1" : "=v"(r) : "v"(x)); return r;
#endif
}

// ---- k_gemm: x@W via bf16-split-A MFMA; W-hi staged in LDS.
//      WxTt tile layout: offset(bh,n,d) = bh*65536 + (n>>5)*2048 + (d>>4)*512
//                        + ((n>>3)&3)*128 + (d&15)*8 + (n&7)
//      Epilogue: exact fp32 ei/ej, pre-scaled by LOG2E. ----
__global__ __launch_bounds__(256) void k_gemm(const float* __restrict__ x,
        const float* __restrict__ W, const float* __restrict__ a,
        u16* __restrict__ WxTt, float* __restrict__ ei, float* __restrict__ ej) {
    __shared__ u16 ldsw[Dd * WSTRIDE];   // 33.8 KiB

    int h = blockIdx.x & 3;
    int group = blockIdx.x >> 2;       // 0..127
    int tid = threadIdx.x;

    {   // stage W-hi for this h into LDS transposed: ldsw[d][k]
        const float* wrow = W + tid * HD + h * 64;   // row k = tid
        #pragma unroll
        for (int c = 0; c < 64; c += 4) {
            float4 wv = *reinterpret_cast<const float4*>(wrow + c);
            u32 p01 = pk_bf16(wv.x, wv.y);
            u32 p23 = pk_bf16(wv.z, wv.w);
            ldsw[(c + 0) * WSTRIDE + tid] = (u16)p01;
            ldsw[(c + 1) * WSTRIDE + tid] = (u16)(p01 >> 16);
            ldsw[(c + 2) * WSTRIDE + tid] = (u16)p23;
            ldsw[(c + 3) * WSTRIDE + tid] = (u16)(p23 >> 16);
        }
    }
    __syncthreads();

    int w = tid >> 6, lane = tid & 63;
    int row_tile = group * 4 + w;      // 0..511
    int m0 = row_tile * 16;
    int b = m0 >> 10;
    int nloc0 = m0 & 1023;
    int c15 = lane & 15;
    int quad = lane >> 4;

    f32x4 acc[4] = {};
    const float* xrow = x + (size_t)(m0 + c15) * Cc + quad * 8;
    #pragma unroll
    for (int k0 = 0; k0 < Cc; k0 += 32) {
        float4 xv0 = *reinterpret_cast<const float4*>(xrow + k0);
        float4 xv1 = *reinterpret_cast<const float4*>(xrow + k0 + 4);
        u32 h0 = pk_bf16(xv0.x, xv0.y);
        u32 h1 = pk_bf16(xv0.z, xv0.w);
        u32 h2 = pk_bf16(xv1.x, xv1.y);
        u32 h3 = pk_bf16(xv1.z, xv1.w);
        u32 l0 = pk_bf16(xv0.x - __builtin_bit_cast(float, h0 << 16),
                         xv0.y - __builtin_bit_cast(float, h0 & 0xffff0000u));
        u32 l1 = pk_bf16(xv0.z - __builtin_bit_cast(float, h1 << 16),
                         xv0.w - __builtin_bit_cast(float, h1 & 0xffff0000u));
        u32 l2 = pk_bf16(xv1.x - __builtin_bit_cast(float, h2 << 16),
                         xv1.y - __builtin_bit_cast(float, h2 & 0xffff0000u));
        u32 l3 = pk_bf16(xv1.z - __builtin_bit_cast(float, h3 << 16),
                         xv1.w - __builtin_bit_cast(float, h3 & 0xffff0000u));
        u32x4 hp = {h0, h1, h2, h3};
        u32x4 lp = {l0, l1, l2, l3};
        bf16x8 ah = __builtin_bit_cast(bf16x8, hp);
        bf16x8 al = __builtin_bit_cast(bf16x8, lp);
        const u16* ldsk = ldsw + k0 + quad * 8;
        #pragma unroll
        for (int t = 0; t < 4; ++t) {
            bf16x8 bh = *reinterpret_cast<const bf16x8*>(ldsk + (t * 16 + c15) * WSTRIDE);
            acc[t] = __builtin_amdgcn_mfma_f32_16x16x32_bf16(ah, bh, acc[t], 0, 0, 0);
            acc[t] = __builtin_amdgcn_mfma_f32_16x16x32_bf16(al, bh, acc[t], 0, 0, 0);
        }
    }
    int bh = b * Hh + h;
    int n_base = nloc0 + quad * 4;
    int chunk = nloc0 >> 5;
    int jq = ((n_base >> 3) & 3);
    int ii = n_base & 7;               // 0 or 4
    size_t tb = (size_t)bh * 65536 + chunk * 2048 + jq * 128 + c15 * 8 + ii;
    #pragma unroll
    for (int t = 0; t < 4; ++t) {
        uint2 pk2;
        pk2.x = pk_bf16(acc[t][0], acc[t][1]);
        pk2.y = pk_bf16(acc[t][2], acc[t][3]);
        *reinterpret_cast<uint2*>(WxTt + tb + t * 512) = pk2;
    }
    float ai[4], aj[4];
    #pragma unroll
    for (int t = 0; t < 4; ++t) {
        ai[t] = a[h * 2 * Dd + t * 16 + c15];
        aj[t] = a[h * 2 * Dd + Dd + t * 16 + c15];
    }
    #pragma unroll
    for (int r = 0; r < 4; ++r) {
        float si = acc[0][r] * ai[0] + acc[1][r] * ai[1] + acc[2][r] * ai[2] + acc[3][r] * ai[3];
        float sj = acc[0][r] * aj[0] + acc[1][r] * aj[1] + acc[2][r] * aj[2] + acc[3][r] * aj[3];
        #pragma unroll
        for (int off = 1; off < 16; off <<= 1) {
            si += __shfl_xor(si, off);
            sj += __shfl_xor(sj, off);
        }
        if (c15 == 0) {
            int n = nloc0 + quad * 4 + r;
            ei[(size_t)bh * Nn + n] = si * LOG2E;
            ej[(size_t)bh * Nn + n] = sj * LOG2E;
        }
    }
}

// ---- k_attn: block = (b, 32-row tile), 512 threads.
//      Phase A: stage 32 adj rows -> LDS bit-mask (with diagonal).
//      Phase B: 8 waves = 4 heads x 2 row-subtiles, full-j sweep,
//               l via ones-column MFMA; no cross-wave combine. ----
__global__ __launch_bounds__(512) void k_attn(const float* __restrict__ adj,
        const u16* __restrict__ WxTt, const float* __restrict__ eis,
        const float* __restrict__ ejs, float* __restrict__ out) {
    __shared__ u32 maskLds[32][33];    // +1 pad: rows spread across banks

    int tid = threadIdx.x;             // 0..511
    int b = blockIdx.x >> 5;           // 0..7
    int tile = blockIdx.x & 31;
    int n0 = tile * 32;

    {   // phase A: thread -> (row, 2 words of 32 bits)
        int row = tid >> 4;            // 0..31
        int w0 = (tid & 15) * 2;       // word index 0..30
        int n = n0 + row;
        const float* arow = adj + ((size_t)(b * Nn + n)) * Nn;
        #pragma unroll
        for (int wi = 0; wi < 2; ++wi) {
            int w = w0 + wi;
            const float* pw = arow + w * 32;
            u32 bits = 0;
            #pragma unroll
            for (int g = 0; g < 8; ++g) {
                float4 v = *reinterpret_cast<const float4*>(pw + g * 4);
                bits |= (__builtin_bit_cast(u32, v.x) != 0u ? 1u : 0u) << (g * 4 + 0);
                bits |= (__builtin_bit_cast(u32, v.y) != 0u ? 1u : 0u) << (g * 4 + 1);
                bits |= (__builtin_bit_cast(u32, v.z) != 0u ? 1u : 0u) << (g * 4 + 2);
                bits |= (__builtin_bit_cast(u32, v.w) != 0u ? 1u : 0u) << (g * 4 + 3);
            }
            if (w == (n >> 5)) bits |= 1u << (n & 31);   // diagonal
            maskLds[row][w] = bits;
        }
    }
    __syncthreads();

    int wid = tid >> 6;                // 0..7
    int lane = tid & 63;
    int h = wid >> 1;                  // head
    int rt = wid & 1;                  // row-subtile (16 rows)
    int bh = b * Hh + h;
    int col = lane & 15;
    int quad = lane >> 4;

    int arow_n = n0 + rt * 16 + col;   // A-fragment row owned by this lane
    float ei_r = eis[(size_t)bh * Nn + arow_n];
    const float* ejrow = ejs + (size_t)bh * Nn + quad * 8;
    const u16* wxplane = WxTt + (size_t)bh * 65536 + lane * 8;
    const u32* mrow = &maskLds[rt * 16 + col][0];

    u16 ov = (col == 0) ? (u16)0x3f80 : (u16)0;
    u16x8 onesu = {ov, ov, ov, ov, ov, ov, ov, ov};
    bf16x8 onesf = __builtin_bit_cast(bf16x8, onesu);

    f32x4 acc[4] = {};
    f32x4 accl = {};
    #pragma unroll 2
    for (int s = 0; s < 32; ++s) {
        int j0 = s * 32;
        u32 mw = mrow[s];
        u32 q0 = (mw >> (quad * 8)) & 0xffu;
        float4 eA = *reinterpret_cast<const float4*>(ejrow + j0);
        float4 eB = *reinterpret_cast<const float4*>(ejrow + j0 + 4);
        float ejv[8] = {eA.x, eA.y, eA.z, eA.w, eB.x, eB.y, eB.z, eB.w};
        u32 p[4];
        #pragma unroll
        for (int pi = 0; pi < 4; ++pi) {
            float sa = ei_r + ejv[2 * pi];
            float sb = ei_r + ejv[2 * pi + 1];
            sa = fmaxf(sa, 0.2f * sa); sb = fmaxf(sb, 0.2f * sb);
            u32 m0 = (((q0 >> (2 * pi)) & 1u) ? 0xffffu : 0u)
                   | (((q0 >> (2 * pi + 1)) & 1u) ? 0xffff0000u : 0u);
            p[pi] = pk_bf16(fast_exp2(sa), fast_exp2(sb)) & m0;
        }
        u32x4 pv = {p[0], p[1], p[2], p[3]};
        bf16x8 afr = __builtin_bit_cast(bf16x8, pv);
        const u16* bbase = wxplane + s * 2048;
        #pragma unroll
        for (int t = 0; t < 4; ++t) {
            bf16x8 bfr = *reinterpret_cast<const bf16x8*>(bbase + t * 512);
            acc[t] = __builtin_amdgcn_mfma_f32_16x16x32_bf16(afr, bfr, acc[t], 0, 0, 0);
        }
        accl = __builtin_amdgcn_mfma_f32_16x16x32_bf16(afr, onesf, accl, 0, 0, 0);
    }

    // epilogue: D col = lane&15 (d), row = quad*4+r; l[row] lives in lane quad*16
    #pragma unroll
    for (int r = 0; r < 4; ++r) {
        float lv = __shfl(accl[r], quad << 4);
        float inv = 1.0f / lv;
        int nr = n0 + rt * 16 + quad * 4 + r;
        size_t obase = ((size_t)(b * Nn + nr)) * HD + h * Dd;
        #pragma unroll
        for (int t = 0; t < 4; ++t) {
            out[obase + t * 16 + col] = acc[t][r] * inv;
        }
    }
}

extern "C" void kernel_launch(void* const* d_in, const int* in_sizes, int n_in,
                              void* d_out, int out_size, void* d_ws, size_t ws_size,
                              hipStream_t stream) {
    const float* x   = (const float*)d_in[0];   // (8,1024,256) fp32
    const float* adj = (const float*)d_in[1];   // (8,1024,1024) fp32
    const float* W   = (const float*)d_in[2];   // (256,256) fp32
    const float* a   = (const float*)d_in[3];   // (1,4,128) fp32
    float* out = (float*)d_out;                 // (8,1024,256) fp32

    char* ws = (char*)d_ws;
    u16*   WxTt = (u16*)(ws);                                 // 4 MiB tile layout
    float* ei   = (float*)(ws + (4u << 20));                  // 128 KiB
    float* ej   = (float*)(ws + (4u << 20) + (128u << 10));   // 128 KiB

    k_gemm<<<512, 256, 0, stream>>>(x, W, a, WxTt, ei, ej);
    k_attn<<<256, 512, 0, stream>>>(adj, WxTt, ei, ej, out);
}

// Round 7
// 115.919 us; speedup vs baseline: 1.2009x; 1.2009x over previous
//
#include <hip/hip_runtime.h>

#define Nn 1024
#define Cc 256
#define Hh 4
#define Dd 64
#define HD 256
#define LOG2E 1.4426950408889634f
#define WSTRIDE 264   // u16 stride for LDS W tile

typedef unsigned short u16;
typedef unsigned int u32;
typedef unsigned char u8;
typedef __bf16 bf16x2 __attribute__((ext_vector_type(2)));
typedef __bf16 bf16x8 __attribute__((ext_vector_type(8)));
typedef float f32x4 __attribute__((ext_vector_type(4)));
typedef u16 u16x8 __attribute__((ext_vector_type(8)));
typedef u32 u32x4 __attribute__((ext_vector_type(4)));

__device__ __forceinline__ float bf2f(u16 v) {
    return __builtin_bit_cast(float, (u32)v << 16);
}
__device__ __forceinline__ u16 f2bf(float f) {
    u32 u = __builtin_bit_cast(u32, f);
    return (u16)((u + 0x7fffu + ((u >> 16) & 1u)) >> 16);
}
__device__ __forceinline__ u32 pk_bf16(float a, float b) {
#if __has_builtin(__builtin_amdgcn_cvt_pk_bf16_f32)
    bf16x2 v = __builtin_amdgcn_cvt_pk_bf16_f32(a, b);
    return __builtin_bit_cast(u32, v);
#else
    return (u32)f2bf(a) | ((u32)f2bf(b) << 16);
#endif
}
__device__ __forceinline__ float fast_exp2(float x) {
#if __has_builtin(__builtin_amdgcn_exp2f)
    return __builtin_amdgcn_exp2f(x);
#else
    float r; asm("v_exp_f32 %0, %1" : "=v"(r) : "v"(x)); return r;
#endif
}

// ---- k_fused: blocks <512 do x@W GEMM (W staged hi-only in LDS);
//      blocks >=512 build the adjacency byte-mask. Independent work,
//      co-scheduled so the HBM sweep overlaps the MFMA GEMM. ----
__global__ __launch_bounds__(256) void k_fused(const float* __restrict__ adj,
        u8* __restrict__ bm, const float* __restrict__ x,
        const float* __restrict__ W, const float* __restrict__ a,
        u16* __restrict__ WxTt, float* __restrict__ ei, float* __restrict__ ej) {
    __shared__ u16 ldsw[Dd * WSTRIDE];   // 33.8 KiB

    if (blockIdx.x >= 512) {
        // ---- adjacency byte-mask (incl. diagonal) ----
        int idx = (blockIdx.x - 512) * 256 + threadIdx.x;   // 0 .. 1048575
        int bn = idx >> 7;
        int byteidx = idx & 127;
        int n = bn & 1023;
        const float* p = adj + ((size_t)bn << 10) + (byteidx << 3);
        float4 v0 = *reinterpret_cast<const float4*>(p);
        float4 v1 = *reinterpret_cast<const float4*>(p + 4);
        u32 bits = 0;
        bits |= (__builtin_bit_cast(u32, v0.x) != 0u) ? 1u : 0u;
        bits |= (__builtin_bit_cast(u32, v0.y) != 0u) ? 2u : 0u;
        bits |= (__builtin_bit_cast(u32, v0.z) != 0u) ? 4u : 0u;
        bits |= (__builtin_bit_cast(u32, v0.w) != 0u) ? 8u : 0u;
        bits |= (__builtin_bit_cast(u32, v1.x) != 0u) ? 16u : 0u;
        bits |= (__builtin_bit_cast(u32, v1.y) != 0u) ? 32u : 0u;
        bits |= (__builtin_bit_cast(u32, v1.z) != 0u) ? 64u : 0u;
        bits |= (__builtin_bit_cast(u32, v1.w) != 0u) ? 128u : 0u;
        if ((n >> 3) == byteidx) bits |= 1u << (n & 7);
        bm[idx] = (u8)bits;
        return;
    }

    // ---- GEMM part: block = (4 row-tiles, one h) ----
    int h = blockIdx.x & 3;
    int group = blockIdx.x >> 2;       // 0..127
    int tid = threadIdx.x;

    {   // stage W-hi for this h into LDS transposed: ldsw[d][k]
        const float* wrow = W + tid * HD + h * 64;   // row k = tid
        #pragma unroll
        for (int c = 0; c < 64; c += 4) {
            float4 wv = *reinterpret_cast<const float4*>(wrow + c);
            u32 p01 = pk_bf16(wv.x, wv.y);
            u32 p23 = pk_bf16(wv.z, wv.w);
            ldsw[(c + 0) * WSTRIDE + tid] = (u16)p01;
            ldsw[(c + 1) * WSTRIDE + tid] = (u16)(p01 >> 16);
            ldsw[(c + 2) * WSTRIDE + tid] = (u16)p23;
            ldsw[(c + 3) * WSTRIDE + tid] = (u16)(p23 >> 16);
        }
    }
    __syncthreads();

    int w = tid >> 6, lane = tid & 63;
    int row_tile = group * 4 + w;      // 0..511
    int m0 = row_tile * 16;
    int b = m0 >> 10;
    int nloc0 = m0 & 1023;
    int c15 = lane & 15;
    int quad = lane >> 4;

    f32x4 acc[4] = {};
    const float* xrow = x + (size_t)(m0 + c15) * Cc + quad * 8;
    #pragma unroll
    for (int k0 = 0; k0 < Cc; k0 += 32) {
        float4 xv0 = *reinterpret_cast<const float4*>(xrow + k0);
        float4 xv1 = *reinterpret_cast<const float4*>(xrow + k0 + 4);
        u32 h0 = pk_bf16(xv0.x, xv0.y);
        u32 h1 = pk_bf16(xv0.z, xv0.w);
        u32 h2 = pk_bf16(xv1.x, xv1.y);
        u32 h3 = pk_bf16(xv1.z, xv1.w);
        u32 l0 = pk_bf16(xv0.x - __builtin_bit_cast(float, h0 << 16),
                         xv0.y - __builtin_bit_cast(float, h0 & 0xffff0000u));
        u32 l1 = pk_bf16(xv0.z - __builtin_bit_cast(float, h1 << 16),
                         xv0.w - __builtin_bit_cast(float, h1 & 0xffff0000u));
        u32 l2 = pk_bf16(xv1.x - __builtin_bit_cast(float, h2 << 16),
                         xv1.y - __builtin_bit_cast(float, h2 & 0xffff0000u));
        u32 l3 = pk_bf16(xv1.z - __builtin_bit_cast(float, h3 << 16),
                         xv1.w - __builtin_bit_cast(float, h3 & 0xffff0000u));
        u32x4 hp = {h0, h1, h2, h3};
        u32x4 lp = {l0, l1, l2, l3};
        bf16x8 ah = __builtin_bit_cast(bf16x8, hp);
        bf16x8 al = __builtin_bit_cast(bf16x8, lp);
        const u16* ldsk = ldsw + k0 + quad * 8;
        #pragma unroll
        for (int t = 0; t < 4; ++t) {
            bf16x8 bh = *reinterpret_cast<const bf16x8*>(ldsk + (t * 16 + c15) * WSTRIDE);
            acc[t] = __builtin_amdgcn_mfma_f32_16x16x32_bf16(ah, bh, acc[t], 0, 0, 0);
            acc[t] = __builtin_amdgcn_mfma_f32_16x16x32_bf16(al, bh, acc[t], 0, 0, 0);
        }
    }
    int bh = b * Hh + h;
    // WxTt tile layout: offset(bh,n,d) = bh*65536 + (n>>5)*2048 + (d>>4)*512
    //                   + ((n>>3)&3)*128 + (d&15)*8 + (n&7)
    int n_base = nloc0 + quad * 4;
    int chunk = nloc0 >> 5;
    int jq = ((n_base >> 3) & 3);
    int ii = n_base & 7;               // 0 or 4
    size_t tb = (size_t)bh * 65536 + chunk * 2048 + jq * 128 + c15 * 8 + ii;
    #pragma unroll
    for (int t = 0; t < 4; ++t) {
        uint2 pk2;
        pk2.x = pk_bf16(acc[t][0], acc[t][1]);
        pk2.y = pk_bf16(acc[t][2], acc[t][3]);
        *reinterpret_cast<uint2*>(WxTt + tb + t * 512) = pk2;
    }
    // ei/ej epilogue (pre-scaled by LOG2E for exp2)
    float ai[4], aj[4];
    #pragma unroll
    for (int t = 0; t < 4; ++t) {
        ai[t] = a[h * 2 * Dd + t * 16 + c15];
        aj[t] = a[h * 2 * Dd + Dd + t * 16 + c15];
    }
    #pragma unroll
    for (int r = 0; r < 4; ++r) {
        float si = acc[0][r] * ai[0] + acc[1][r] * ai[1] + acc[2][r] * ai[2] + acc[3][r] * ai[3];
        float sj = acc[0][r] * aj[0] + acc[1][r] * aj[1] + acc[2][r] * aj[2] + acc[3][r] * aj[3];
        #pragma unroll
        for (int off = 1; off < 16; off <<= 1) {
            si += __shfl_xor(si, off);
            sj += __shfl_xor(sj, off);
        }
        if (c15 == 0) {
            int n = nloc0 + quad * 4 + r;
            ei[(size_t)bh * Nn + n] = si * LOG2E;
            ej[(size_t)bh * Nn + n] = sj * LOG2E;
        }
    }
}

// ---- k_attn: block = (bh, 64-row tile), 256 threads.
//      4 waves split j into quarters; each wave holds 4 row-subtiles
//      (B-fragments reused 4x). LDS combine at the end.
//      l via ones-column MFMA per row-subtile. ----
__global__ __launch_bounds__(256) void k_attn(const u8* __restrict__ bm,
        const u16* __restrict__ WxTt, const float* __restrict__ eis,
        const float* __restrict__ ejs, float* __restrict__ out) {
    int widx = threadIdx.x >> 6;     // j-quarter
    int lane = threadIdx.x & 63;
    int bh = blockIdx.x >> 4;        // 0..31
    int tile = blockIdx.x & 15;      // 64-row tile
    int b = bh >> 2, h = bh & 3;
    int n0 = tile * 64;
    int col = lane & 15;
    int quad = lane >> 4;

    float ei_rb[4];
    const u8* mb_rb[4];
    #pragma unroll
    for (int rb = 0; rb < 4; ++rb) {
        int rn = n0 + rb * 16 + col;
        ei_rb[rb] = eis[(size_t)bh * Nn + rn];
        mb_rb[rb] = bm + ((size_t)(b * Nn + rn)) * 128;
    }
    const float* ejrow = ejs + (size_t)bh * Nn + quad * 8;
    const u16* wxplane = WxTt + (size_t)bh * 65536 + lane * 8;

    u16 ov = (col == 0) ? (u16)0x3f80 : (u16)0;
    u16x8 onesu = {ov, ov, ov, ov, ov, ov, ov, ov};
    bf16x8 onesf = __builtin_bit_cast(bf16x8, onesu);

    f32x4 acc[4][4] = {};
    f32x4 accl[4] = {};
    int jbase = widx * 256;
    for (int s = 0; s < 8; ++s) {
        int j0 = jbase + s * 32;
        float4 eA = *reinterpret_cast<const float4*>(ejrow + j0);
        float4 eB = *reinterpret_cast<const float4*>(ejrow + j0 + 4);
        float ejv[8] = {eA.x, eA.y, eA.z, eA.w, eB.x, eB.y, eB.z, eB.w};
        // B fragments for this j-step (shared by all 4 row-subtiles)
        const u16* bbase = wxplane + (j0 >> 5) * 2048;
        bf16x8 bfr[4];
        #pragma unroll
        for (int t = 0; t < 4; ++t)
            bfr[t] = *reinterpret_cast<const bf16x8*>(bbase + t * 512);
        #pragma unroll
        for (int rb = 0; rb < 4; ++rb) {
            u32 mw = *reinterpret_cast<const u32*>(mb_rb[rb] + (j0 >> 3));
            u32 q0 = (mw >> (quad * 8)) & 0xffu;
            float ei_r = ei_rb[rb];
            u32 p[4];
            #pragma unroll
            for (int pi = 0; pi < 4; ++pi) {
                float sa = ei_r + ejv[2 * pi];
                float sb = ei_r + ejv[2 * pi + 1];
                sa = fmaxf(sa, 0.2f * sa); sb = fmaxf(sb, 0.2f * sb);
                u32 m0 = (((q0 >> (2 * pi)) & 1u) ? 0xffffu : 0u)
                       | (((q0 >> (2 * pi + 1)) & 1u) ? 0xffff0000u : 0u);
                p[pi] = pk_bf16(fast_exp2(sa), fast_exp2(sb)) & m0;
            }
            u32x4 pv = {p[0], p[1], p[2], p[3]};
            bf16x8 afr = __builtin_bit_cast(bf16x8, pv);
            #pragma unroll
            for (int t = 0; t < 4; ++t)
                acc[rb][t] = __builtin_amdgcn_mfma_f32_16x16x32_bf16(afr, bfr[t], acc[rb][t], 0, 0, 0);
            accl[rb] = __builtin_amdgcn_mfma_f32_16x16x32_bf16(afr, onesf, accl[rb], 0, 0, 0);
        }
    }

    // ---- cross-wave combine in LDS ----
    __shared__ f32x4 lacc[4][16][64];     // 64 KiB
    __shared__ float lsums[4][4][16];     // 1 KiB
    #pragma unroll
    for (int rb = 0; rb < 4; ++rb) {
        #pragma unroll
        for (int t = 0; t < 4; ++t)
            lacc[widx][rb * 4 + t][lane] = acc[rb][t];
        if (col == 0) {
            #pragma unroll
            for (int r = 0; r < 4; ++r)
                lsums[widx][rb][quad * 4 + r] = accl[rb][r];
        }
    }
    __syncthreads();
    #pragma unroll
    for (int pp = 0; pp < 4; ++pp) {
        int p = widx * 4 + pp;
        int rb = p >> 2, t = p & 3;
        f32x4 v = lacc[0][p][lane];
        v += lacc[1][p][lane];
        v += lacc[2][p][lane];
        v += lacc[3][p][lane];
        #pragma unroll
        for (int r = 0; r < 4; ++r) {
            int rloc = quad * 4 + r;
            float lv = lsums[0][rb][rloc] + lsums[1][rb][rloc]
                     + lsums[2][rb][rloc] + lsums[3][rb][rloc];
            int nr = n0 + rb * 16 + rloc;
            out[(size_t)(b * Nn + nr) * HD + h * Dd + t * 16 + col] = v[r] * (1.0f / lv);
        }
    }
}

extern "C" void kernel_launch(void* const* d_in, const int* in_sizes, int n_in,
                              void* d_out, int out_size, void* d_ws, size_t ws_size,
                              hipStream_t stream) {
    const float* x   = (const float*)d_in[0];   // (8,1024,256) fp32
    const float* adj = (const float*)d_in[1];   // (8,1024,1024) fp32
    const float* W   = (const float*)d_in[2];   // (256,256) fp32
    const float* a   = (const float*)d_in[3];   // (1,4,128) fp32
    float* out = (float*)d_out;                 // (8,1024,256) fp32

    char* ws = (char*)d_ws;
    u16*   WxTt = (u16*)(ws);                                 // 4 MiB tile layout
    float* ei   = (float*)(ws + (4u << 20));                  // 128 KiB
    float* ej   = (float*)(ws + (4u << 20) + (128u << 10));   // 128 KiB
    u8*    bm   = (u8*)(ws + (4u << 20) + (256u << 10));      // 1 MiB

    k_fused<<<4608, 256, 0, stream>>>(adj, bm, x, W, a, WxTt, ei, ej);
    k_attn<<<512, 256, 0, stream>>>(bm, WxTt, ei, ej, out);
}

// Round 8
// 114.588 us; speedup vs baseline: 1.2149x; 1.0116x over previous
//
#include <hip/hip_runtime.h>

#define Nn 1024
#define Cc 256
#define Hh 4
#define Dd 64
#define HD 256
#define LOG2E 1.4426950408889634f
#define WSTRIDE 264   // u16 stride for LDS W tile

typedef unsigned short u16;
typedef unsigned int u32;
typedef unsigned char u8;
typedef __bf16 bf16x2 __attribute__((ext_vector_type(2)));
typedef __bf16 bf16x8 __attribute__((ext_vector_type(8)));
typedef float f32x4 __attribute__((ext_vector_type(4)));
typedef u16 u16x8 __attribute__((ext_vector_type(8)));
typedef u32 u32x4 __attribute__((ext_vector_type(4)));

__device__ __forceinline__ float bf2f(u16 v) {
    return __builtin_bit_cast(float, (u32)v << 16);
}
__device__ __forceinline__ u16 f2bf(float f) {
    u32 u = __builtin_bit_cast(u32, f);
    return (u16)((u + 0x7fffu + ((u >> 16) & 1u)) >> 16);
}
__device__ __forceinline__ u32 pk_bf16(float a, float b) {
#if __has_builtin(__builtin_amdgcn_cvt_pk_bf16_f32)
    bf16x2 v = __builtin_amdgcn_cvt_pk_bf16_f32(a, b);
    return __builtin_bit_cast(u32, v);
#else
    return (u32)f2bf(a) | ((u32)f2bf(b) << 16);
#endif
}
__device__ __forceinline__ float fast_exp2(float x) {
#if __has_builtin(__builtin_amdgcn_exp2f)
    return __builtin_amdgcn_exp2f(x);
#else
    float r; asm("v_exp_f32 %0, %1" : "=v"(r) : "v"(x)); return r;
#endif
}

// ---- k_fused: blocks <512 do x@W GEMM (W staged hi-only in LDS);
//      blocks >=512 build the adjacency byte-mask. Independent work,
//      co-scheduled so the HBM sweep overlaps the MFMA GEMM. ----
__global__ __launch_bounds__(256) void k_fused(const float* __restrict__ adj,
        u8* __restrict__ bm, const float* __restrict__ x,
        const float* __restrict__ W, const float* __restrict__ a,
        u16* __restrict__ WxTt, float* __restrict__ ei, float* __restrict__ ej) {
    __shared__ u16 ldsw[Dd * WSTRIDE];   // 33.8 KiB

    if (blockIdx.x >= 512) {
        // ---- adjacency byte-mask (incl. diagonal) ----
        int idx = (blockIdx.x - 512) * 256 + threadIdx.x;   // 0 .. 1048575
        int bn = idx >> 7;
        int byteidx = idx & 127;
        int n = bn & 1023;
        const float* p = adj + ((size_t)bn << 10) + (byteidx << 3);
        float4 v0 = *reinterpret_cast<const float4*>(p);
        float4 v1 = *reinterpret_cast<const float4*>(p + 4);
        u32 bits = 0;
        bits |= (__builtin_bit_cast(u32, v0.x) != 0u) ? 1u : 0u;
        bits |= (__builtin_bit_cast(u32, v0.y) != 0u) ? 2u : 0u;
        bits |= (__builtin_bit_cast(u32, v0.z) != 0u) ? 4u : 0u;
        bits |= (__builtin_bit_cast(u32, v0.w) != 0u) ? 8u : 0u;
        bits |= (__builtin_bit_cast(u32, v1.x) != 0u) ? 16u : 0u;
        bits |= (__builtin_bit_cast(u32, v1.y) != 0u) ? 32u : 0u;
        bits |= (__builtin_bit_cast(u32, v1.z) != 0u) ? 64u : 0u;
        bits |= (__builtin_bit_cast(u32, v1.w) != 0u) ? 128u : 0u;
        if ((n >> 3) == byteidx) bits |= 1u << (n & 7);
        bm[idx] = (u8)bits;
        return;
    }

    // ---- GEMM part: block = (4 row-tiles, one h) ----
    int h = blockIdx.x & 3;
    int group = blockIdx.x >> 2;       // 0..127
    int tid = threadIdx.x;

    {   // stage W-hi for this h into LDS transposed: ldsw[d][k]
        const float* wrow = W + tid * HD + h * 64;   // row k = tid
        #pragma unroll
        for (int c = 0; c < 64; c += 4) {
            float4 wv = *reinterpret_cast<const float4*>(wrow + c);
            u32 p01 = pk_bf16(wv.x, wv.y);
            u32 p23 = pk_bf16(wv.z, wv.w);
            ldsw[(c + 0) * WSTRIDE + tid] = (u16)p01;
            ldsw[(c + 1) * WSTRIDE + tid] = (u16)(p01 >> 16);
            ldsw[(c + 2) * WSTRIDE + tid] = (u16)p23;
            ldsw[(c + 3) * WSTRIDE + tid] = (u16)(p23 >> 16);
        }
    }
    __syncthreads();

    int w = tid >> 6, lane = tid & 63;
    int row_tile = group * 4 + w;      // 0..511
    int m0 = row_tile * 16;
    int b = m0 >> 10;
    int nloc0 = m0 & 1023;
    int c15 = lane & 15;
    int quad = lane >> 4;

    f32x4 acc[4] = {};
    const float* xrow = x + (size_t)(m0 + c15) * Cc + quad * 8;
    #pragma unroll
    for (int k0 = 0; k0 < Cc; k0 += 32) {
        float4 xv0 = *reinterpret_cast<const float4*>(xrow + k0);
        float4 xv1 = *reinterpret_cast<const float4*>(xrow + k0 + 4);
        u32 h0 = pk_bf16(xv0.x, xv0.y);
        u32 h1 = pk_bf16(xv0.z, xv0.w);
        u32 h2 = pk_bf16(xv1.x, xv1.y);
        u32 h3 = pk_bf16(xv1.z, xv1.w);
        u32 l0 = pk_bf16(xv0.x - __builtin_bit_cast(float, h0 << 16),
                         xv0.y - __builtin_bit_cast(float, h0 & 0xffff0000u));
        u32 l1 = pk_bf16(xv0.z - __builtin_bit_cast(float, h1 << 16),
                         xv0.w - __builtin_bit_cast(float, h1 & 0xffff0000u));
        u32 l2 = pk_bf16(xv1.x - __builtin_bit_cast(float, h2 << 16),
                         xv1.y - __builtin_bit_cast(float, h2 & 0xffff0000u));
        u32 l3 = pk_bf16(xv1.z - __builtin_bit_cast(float, h3 << 16),
                         xv1.w - __builtin_bit_cast(float, h3 & 0xffff0000u));
        u32x4 hp = {h0, h1, h2, h3};
        u32x4 lp = {l0, l1, l2, l3};
        bf16x8 ah = __builtin_bit_cast(bf16x8, hp);
        bf16x8 al = __builtin_bit_cast(bf16x8, lp);
        const u16* ldsk = ldsw + k0 + quad * 8;
        #pragma unroll
        for (int t = 0; t < 4; ++t) {
            bf16x8 bh = *reinterpret_cast<const bf16x8*>(ldsk + (t * 16 + c15) * WSTRIDE);
            acc[t] = __builtin_amdgcn_mfma_f32_16x16x32_bf16(ah, bh, acc[t], 0, 0, 0);
            acc[t] = __builtin_amdgcn_mfma_f32_16x16x32_bf16(al, bh, acc[t], 0, 0, 0);
        }
    }
    int bh = b * Hh + h;
    // WxTt tile layout: offset(bh,n,d) = bh*65536 + (n>>5)*2048 + (d>>4)*512
    //                   + ((n>>3)&3)*128 + (d&15)*8 + (n&7)
    int n_base = nloc0 + quad * 4;
    int chunk = nloc0 >> 5;
    int jq = ((n_base >> 3) & 3);
    int ii = n_base & 7;               // 0 or 4
    size_t tb = (size_t)bh * 65536 + chunk * 2048 + jq * 128 + c15 * 8 + ii;
    #pragma unroll
    for (int t = 0; t < 4; ++t) {
        uint2 pk2;
        pk2.x = pk_bf16(acc[t][0], acc[t][1]);
        pk2.y = pk_bf16(acc[t][2], acc[t][3]);
        *reinterpret_cast<uint2*>(WxTt + tb + t * 512) = pk2;
    }
    // ei/ej epilogue (pre-scaled by LOG2E for exp2)
    float ai[4], aj[4];
    #pragma unroll
    for (int t = 0; t < 4; ++t) {
        ai[t] = a[h * 2 * Dd + t * 16 + c15];
        aj[t] = a[h * 2 * Dd + Dd + t * 16 + c15];
    }
    #pragma unroll
    for (int r = 0; r < 4; ++r) {
        float si = acc[0][r] * ai[0] + acc[1][r] * ai[1] + acc[2][r] * ai[2] + acc[3][r] * ai[3];
        float sj = acc[0][r] * aj[0] + acc[1][r] * aj[1] + acc[2][r] * aj[2] + acc[3][r] * aj[3];
        #pragma unroll
        for (int off = 1; off < 16; off <<= 1) {
            si += __shfl_xor(si, off);
            sj += __shfl_xor(sj, off);
        }
        if (c15 == 0) {
            int n = nloc0 + quad * 4 + r;
            ei[(size_t)bh * Nn + n] = si * LOG2E;
            ej[(size_t)bh * Nn + n] = sj * LOG2E;
        }
    }
}

// ---- k_attn: out = softmax(e) @ Wx per (b,h).
//      Block = (bh, 32-row tile); 4 waves split j into quarters; LDS combine.
//      l via extra MFMAs vs ones-column B-fragment. ----
__global__ __launch_bounds__(256) void k_attn(const u8* __restrict__ bm,
        const u16* __restrict__ WxTt, const float* __restrict__ eis,
        const float* __restrict__ ejs, float* __restrict__ out) {
    int widx = threadIdx.x >> 6;     // j-quarter
    int lane = threadIdx.x & 63;
    int bh = blockIdx.x >> 5;        // 0..31
    int tile = blockIdx.x & 31;      // 32-row tile
    int b = bh >> 2, h = bh & 3;
    int n0 = tile * 32;
    int col = lane & 15;
    int quad = lane >> 4;

    int r0 = n0 + col, r1 = n0 + 16 + col;
    float ei0 = eis[(size_t)bh * Nn + r0];
    float ei1 = eis[(size_t)bh * Nn + r1];
    const u8* mb0 = bm + ((size_t)(b * Nn + r0)) * 128;
    const u8* mb1 = bm + ((size_t)(b * Nn + r1)) * 128;
    const float* ejrow = ejs + (size_t)bh * Nn + quad * 8;
    const u16* wxplane = WxTt + (size_t)bh * 65536 + lane * 8;

    u16 ov = (col == 0) ? (u16)0x3f80 : (u16)0;
    u16x8 onesu = {ov, ov, ov, ov, ov, ov, ov, ov};
    bf16x8 onesf = __builtin_bit_cast(bf16x8, onesu);

    f32x4 acc0[4] = {}, acc1[4] = {};
    f32x4 accl0 = {}, accl1 = {};
    int jbase = widx * 256;
    #pragma unroll 2
    for (int s = 0; s < 8; ++s) {
        int j0 = jbase + s * 32;
        u32 mw0 = *reinterpret_cast<const u32*>(mb0 + (j0 >> 3));
        u32 mw1 = *reinterpret_cast<const u32*>(mb1 + (j0 >> 3));
        u32 q0 = (mw0 >> (quad * 8)) & 0xffu;
        u32 q1 = (mw1 >> (quad * 8)) & 0xffu;
        float4 eA = *reinterpret_cast<const float4*>(ejrow + j0);
        float4 eB = *reinterpret_cast<const float4*>(ejrow + j0 + 4);
        float ejv[8] = {eA.x, eA.y, eA.z, eA.w, eB.x, eB.y, eB.z, eB.w};
        u32 p0[4], p1[4];
        #pragma unroll
        for (int pi = 0; pi < 4; ++pi) {
            float e_lo = ejv[2 * pi], e_hi = ejv[2 * pi + 1];
            float sa = ei0 + e_lo, sb = ei0 + e_hi;
            sa = fmaxf(sa, 0.2f * sa); sb = fmaxf(sb, 0.2f * sb);
            u32 m0 = (((q0 >> (2 * pi)) & 1u) ? 0xffffu : 0u)
                   | (((q0 >> (2 * pi + 1)) & 1u) ? 0xffff0000u : 0u);
            p0[pi] = pk_bf16(fast_exp2(sa), fast_exp2(sb)) & m0;
            float sc = ei1 + e_lo, sd = ei1 + e_hi;
            sc = fmaxf(sc, 0.2f * sc); sd = fmaxf(sd, 0.2f * sd);
            u32 m1 = (((q1 >> (2 * pi)) & 1u) ? 0xffffu : 0u)
                   | (((q1 >> (2 * pi + 1)) & 1u) ? 0xffff0000u : 0u);
            p1[pi] = pk_bf16(fast_exp2(sc), fast_exp2(sd)) & m1;
        }
        u32x4 pv0 = {p0[0], p0[1], p0[2], p0[3]};
        u32x4 pv1 = {p1[0], p1[1], p1[2], p1[3]};
        bf16x8 a0 = __builtin_bit_cast(bf16x8, pv0);
        bf16x8 a1 = __builtin_bit_cast(bf16x8, pv1);
        const u16* bbase = wxplane + (j0 >> 5) * 2048;
        #pragma unroll
        for (int t = 0; t < 4; ++t) {
            bf16x8 bfr = *reinterpret_cast<const bf16x8*>(bbase + t * 512);
            acc0[t] = __builtin_amdgcn_mfma_f32_16x16x32_bf16(a0, bfr, acc0[t], 0, 0, 0);
            acc1[t] = __builtin_amdgcn_mfma_f32_16x16x32_bf16(a1, bfr, acc1[t], 0, 0, 0);
        }
        accl0 = __builtin_amdgcn_mfma_f32_16x16x32_bf16(a0, onesf, accl0, 0, 0, 0);
        accl1 = __builtin_amdgcn_mfma_f32_16x16x32_bf16(a1, onesf, accl1, 0, 0, 0);
    }

    __shared__ f32x4 lacc[4][8][64];      // 32 KiB
    __shared__ float lsums[4][2][16];
    #pragma unroll
    for (int t = 0; t < 4; ++t) {
        lacc[widx][t][lane] = acc0[t];
        lacc[widx][4 + t][lane] = acc1[t];
    }
    if (col == 0) {
        #pragma unroll
        for (int r = 0; r < 4; ++r) {
            lsums[widx][0][quad * 4 + r] = accl0[r];
            lsums[widx][1][quad * 4 + r] = accl1[r];
        }
    }
    __syncthreads();
    #pragma unroll
    for (int pp = 0; pp < 2; ++pp) {
        int p = widx * 2 + pp;
        int f = p >> 2, t = p & 3;
        f32x4 v = lacc[0][p][lane];
        v += lacc[1][p][lane];
        v += lacc[2][p][lane];
        v += lacc[3][p][lane];
        #pragma unroll
        for (int r = 0; r < 4; ++r) {
            int rloc = quad * 4 + r;
            float lv = lsums[0][f][rloc] + lsums[1][f][rloc]
                     + lsums[2][f][rloc] + lsums[3][f][rloc];
            int nr = n0 + f * 16 + rloc;
            out[(size_t)(b * Nn + nr) * HD + h * Dd + t * 16 + col] = v[r] * (1.0f / lv);
        }
    }
}

extern "C" void kernel_launch(void* const* d_in, const int* in_sizes, int n_in,
                              void* d_out, int out_size, void* d_ws, size_t ws_size,
                              hipStream_t stream) {
    const float* x   = (const float*)d_in[0];   // (8,1024,256) fp32
    const float* adj = (const float*)d_in[1];   // (8,1024,1024) fp32
    const float* W   = (const float*)d_in[2];   // (256,256) fp32
    const float* a   = (const float*)d_in[3];   // (1,4,128) fp32
    float* out = (float*)d_out;                 // (8,1024,256) fp32

    char* ws = (char*)d_ws;
    u16*   WxTt = (u16*)(ws);                           // 4 MiB tile layout
    float* ei   = (float*)(ws + (4u << 20));            // 128 KiB
    float* ej   = (float*)(ws + (4u << 20) + (128u << 10));   // 128 KiB
    u8*    bm   = (u8*)(ws + (4u << 20) + (256u << 10));      // 1 MiB

    k_fused<<<4608, 256, 0, stream>>>(adj, bm, x, W, a, WxTt, ei, ej);
    k_attn<<<1024, 256, 0, stream>>>(bm, WxTt, ei, ej, out);
}